// Round 4
// baseline (73.616 us; speedup 1.0000x reference)
//
#include <hip/hip_runtime.h>

#define NHEADS 16
#define HDIM   64
#define NFEAT  32
#define PDIM   16
#define NQUAD  2
#define GB     8      // b's processed per wave
#define WAVES_PB 4    // waves per 256-thread block

typedef float f32x4 __attribute__((ext_vector_type(4)));

// out[b, r, h, p, m] flat = b*16384 + r*8192 + h*512 + p*32 + m
__global__ __launch_bounds__(256, 4)
void slay_kernel(const float* __restrict__ x,
                 const float* __restrict__ omega,
                 const float* __restrict__ anchors,
                 const float* __restrict__ qn,
                 const float* __restrict__ qw,
                 float* __restrict__ out)
{
    // per-wave buffers (wave_barrier only); s_anch is block-shared, read-only
    __shared__ __align__(16) float s_xn  [WAVES_PB][64];
    __shared__ __align__(16) float s_prf [WAVES_PB][64];
    __shared__ __align__(16) float s_poly[WAVES_PB][16];
    __shared__ __align__(16) float s_anch[PDIM][68];   // +4 pad: spread banks across p

    const int tid  = threadIdx.x;
    const int wv   = tid >> 6;
    const int lane = tid & 63;
    const int h    = blockIdx.x & 15;
    const int b0   = ((blockIdx.x >> 4) * WAVES_PB + wv) * GB;

    const int r = lane >> 5;   // quadrature node index
    const int m = lane & 31;   // feature index
    const int p = lane & 15;   // poly index (4x redundant)
    const int g = lane >> 4;   // d-group for poly partial dot

    // stage anchors once per block (read-only thereafter)
    for (int i = tid; i < PDIM * HDIM; i += 256)
        s_anch[i >> 6][i & 63] = anchors[i];

    const float sR     = fmaxf(qn[r], 1e-6f);
    const float sq2s   = sqrtf(2.0f * sR);
    const float scaleR = sqrtf(fmaxf(qw[r], 1e-6f)) * (1.0f / sqrtf(32.0f + 1e-6f));

    // preload omega column om[d] = omega[r][h][d][m] (L2-resident after warmup)
    float om[64];
    {
        const float* oc = omega + ((size_t)(r * NHEADS + h) * HDIM) * NFEAT + m;
        #pragma unroll
        for (int d = 0; d < 64; ++d) om[d] = oc[(size_t)d * NFEAT];
    }

    __syncthreads();   // anchors visible block-wide (one-time; no stores in flight yet)

    // software-pipelined x loads (depth 2, only 2 regs)
    const float* xb = x + (size_t)b0 * (NHEADS * HDIM) + h * HDIM + lane;
    float xcur = __builtin_nontemporal_load(xb);

    #pragma unroll 2
    for (int bb = 0; bb < GB; ++bb) {
        float xnext = 0.0f;
        if (bb + 1 < GB)
            xnext = __builtin_nontemporal_load(xb + (size_t)(bb + 1) * (NHEADS * HDIM));

        // ---- normalize (lane = d) ----
        float ss = xcur * xcur;
        #pragma unroll
        for (int off = 32; off > 0; off >>= 1) ss += __shfl_xor(ss, off, 64);
        const float xn = xcur * __builtin_amdgcn_rcpf(fmaxf(sqrtf(ss), 1e-4f));

        // stage xn per-wave (in-wave DS ordering; fences are compile-time only)
        __builtin_amdgcn_wave_barrier();
        s_xn[wv][lane] = xn;
        __builtin_amdgcn_wave_barrier();

        // ---- prf dot: LDS broadcast reads (same-addr = free broadcast) ----
        float a0 = 0.f, a1 = 0.f, a2 = 0.f, a3 = 0.f;
        #pragma unroll
        for (int d4 = 0; d4 < 16; ++d4) {
            const f32x4 xq = *(const f32x4*)&s_xn[wv][d4 * 4];
            a0 = fmaf(xq.x, om[d4 * 4 + 0], a0);
            a1 = fmaf(xq.y, om[d4 * 4 + 1], a1);
            a2 = fmaf(xq.z, om[d4 * 4 + 2], a2);
            a3 = fmaf(xq.w, om[d4 * 4 + 3], a3);
        }
        const float accR = (a0 + a1) + (a2 + a3);

        // ---- poly dot: 16-d slice per lane-group, anchors from LDS ----
        float p0 = 0.f, p1 = 0.f, p2 = 0.f, p3 = 0.f;
        {
            const float* xs = &s_xn[wv][g * 16];
            const float* as = &s_anch[p][g * 16];
            #pragma unroll
            for (int q4 = 0; q4 < 4; ++q4) {
                const f32x4 xq = *(const f32x4*)(xs + q4 * 4);
                const f32x4 aq = *(const f32x4*)(as + q4 * 4);
                p0 = fmaf(xq.x, aq.x, p0);
                p1 = fmaf(xq.y, aq.y, p1);
                p2 = fmaf(xq.z, aq.z, p2);
                p3 = fmaf(xq.w, aq.w, p3);
            }
        }
        float accP = (p0 + p1) + (p2 + p3);
        accP += __shfl_xor(accP, 16, 64);   // combine the 4 d-groups
        accP += __shfl_xor(accP, 32, 64);

        // ---- feature epilogues ----
        const float arg  = fminf(fmaxf(accR * sq2s - sR, -20.f), 20.f);
        const float prf  = expf(arg) * scaleR;
        const float pc   = fminf(fmaxf(accP, -1.f), 1.f);
        const float poly = pc * pc * 0.25f;

        // ---- stage per-wave, expand + write ----
        __builtin_amdgcn_wave_barrier();
        s_prf[wv][lane] = prf;
        if (lane < 16) s_poly[wv][lane] = poly;
        __builtin_amdgcn_wave_barrier();

        float* ob = out + (size_t)(b0 + bb) * (NQUAD * NHEADS * PDIM * NFEAT)
                        + (size_t)h * (PDIM * NFEAT);
        #pragma unroll
        for (int i = 0; i < 4; ++i) {
            const int rr = i >> 1;
            const int pp = (i * 8 + (lane >> 3)) & 15;
            const float pf = s_poly[wv][pp];
            const f32x4 pr = *(const f32x4*)&s_prf[wv][rr * 32 + (lane & 7) * 4];
            f32x4 v;
            v.x = pf * pr.x; v.y = pf * pr.y; v.z = pf * pr.z; v.w = pf * pr.w;
            __builtin_nontemporal_store(v,
                (f32x4*)(ob + (size_t)rr * (NHEADS * PDIM * NFEAT)
                            + (i & 1) * 256 + lane * 4));
        }
        xcur = xnext;
    }
}

extern "C" void kernel_launch(void* const* d_in, const int* in_sizes, int n_in,
                              void* d_out, int out_size, void* d_ws, size_t ws_size,
                              hipStream_t stream)
{
    const float* x       = (const float*)d_in[0];
    const float* omega   = (const float*)d_in[1];
    const float* anchors = (const float*)d_in[2];
    const float* qn      = (const float*)d_in[3];
    const float* qw      = (const float*)d_in[4];
    float* out = (float*)d_out;

    const int Bsz = in_sizes[0] / (NHEADS * HDIM);          // 4096
    dim3 grid((Bsz / (WAVES_PB * GB)) * NHEADS);            // 128 * 16 = 2048
    slay_kernel<<<grid, 256, 0, stream>>>(x, omega, anchors, qn, qw, out);
}

// Round 5
// 63.061 us; speedup vs baseline: 1.1674x; 1.1674x over previous
//
#include <hip/hip_runtime.h>

#define NHEADS 16
#define HDIM   64
#define NFEAT  32
#define PDIM   16
#define NQUAD  2
#define GB     8      // b's processed per wave
#define WAVES_PB 4    // waves per 256-thread block

typedef float f32x4 __attribute__((ext_vector_type(4)));

// out[b, r, h, p, m] flat = b*16384 + r*8192 + h*512 + p*32 + m
__global__ __launch_bounds__(256, 4)
void slay_kernel(const float* __restrict__ x,
                 const float* __restrict__ omega,
                 const float* __restrict__ anchors,
                 const float* __restrict__ qn,
                 const float* __restrict__ qw,
                 float* __restrict__ out)
{
    // all buffers are PER-WAVE: no __syncthreads needed, wave_barrier only
    __shared__ __align__(16) float s_xn [WAVES_PB][64];
    __shared__ __align__(16) float s_prf[WAVES_PB][64];
    __shared__ __align__(16) float s_poly[WAVES_PB][16];

    const int tid  = threadIdx.x;
    const int wv   = tid >> 6;
    const int lane = tid & 63;

    // XCD-aware remap (bijective, grid=2048): consecutive blocks on ONE XCD
    // (i % 8 == k) cover all 16 h of the same 32-b range -> the XCD's
    // in-flight write set is a dense contiguous 2MB region (L2-resident),
    // so L2->HBM evictions stream with high row-buffer locality.
    const int i  = blockIdx.x;
    const int k  = i & 7;          // XCD
    const int t  = i >> 3;         // sequence position within XCD
    const int h  = t & 15;
    const int bg = (t >> 4) * 8 + k;   // b-group in [0,128)
    const int b0 = (bg * WAVES_PB + wv) * GB;

    const int r = lane >> 5;   // quadrature node index
    const int m = lane & 31;   // feature index
    const int p = lane & 15;   // poly index (4x redundant)
    const int g = lane >> 4;   // d-group for poly partial dot

    const float sR     = fmaxf(qn[r], 1e-6f);
    const float sq2s   = sqrtf(2.0f * sR);
    const float scaleR = sqrtf(fmaxf(qw[r], 1e-6f)) / sqrtf(32.0f + 1e-6f);

    // preload omega column om[d] = omega[r][h][d][m]
    float om[64];
    {
        const float* oc = omega + ((size_t)(r * NHEADS + h) * HDIM) * NFEAT + m;
        #pragma unroll
        for (int d = 0; d < 64; ++d) om[d] = oc[(size_t)d * NFEAT];
    }
    // anchors slice: an[dd] = anchors[p][g*16 + dd]  (only 16 regs)
    float an[16];
    {
        const float* ac = anchors + p * HDIM + g * 16;
        #pragma unroll
        for (int dd = 0; dd < 16; ++dd) an[dd] = ac[dd];
    }

    // hoist all GB x loads (independent; overlap their latency)
    float xvv[GB];
    {
        const float* xb = x + (size_t)b0 * (NHEADS * HDIM) + h * HDIM + lane;
        #pragma unroll
        for (int bb = 0; bb < GB; ++bb) xvv[bb] = xb[(size_t)bb * (NHEADS * HDIM)];
    }

    #pragma unroll
    for (int bb = 0; bb < GB; ++bb) {
        const int b = b0 + bb;

        // ---- normalize x[b, h, :] (lane = d) ----
        float ss = xvv[bb] * xvv[bb];
        #pragma unroll
        for (int off = 32; off > 0; off >>= 1) ss += __shfl_xor(ss, off, 64);
        const float xn = xvv[bb] / fmaxf(sqrtf(ss), 1e-4f);

        // stage xn per-wave for the poly path (compile-time fences only)
        __builtin_amdgcn_wave_barrier();
        s_xn[wv][lane] = xn;
        __builtin_amdgcn_wave_barrier();

        // ---- prf dot: readlane broadcast, 4 independent accum chains ----
        float a0 = 0.f, a1 = 0.f, a2 = 0.f, a3 = 0.f;
        #pragma unroll
        for (int d = 0; d < 64; d += 4) {
            const float s0 = __uint_as_float(__builtin_amdgcn_readlane(__float_as_uint(xn), d + 0));
            const float s1 = __uint_as_float(__builtin_amdgcn_readlane(__float_as_uint(xn), d + 1));
            const float s2 = __uint_as_float(__builtin_amdgcn_readlane(__float_as_uint(xn), d + 2));
            const float s3 = __uint_as_float(__builtin_amdgcn_readlane(__float_as_uint(xn), d + 3));
            a0 = fmaf(s0, om[d + 0], a0);
            a1 = fmaf(s1, om[d + 1], a1);
            a2 = fmaf(s2, om[d + 2], a2);
            a3 = fmaf(s3, om[d + 3], a3);
        }
        const float accR = (a0 + a1) + (a2 + a3);

        // ---- poly dot: this lane's 16-d slice from LDS, group-reduce ----
        float p0 = 0.f, p1 = 0.f, p2 = 0.f, p3 = 0.f;
        #pragma unroll
        for (int q4 = 0; q4 < 4; ++q4) {
            const f32x4 xq = *(const f32x4*)&s_xn[wv][g * 16 + q4 * 4];
            p0 = fmaf(xq.x, an[q4 * 4 + 0], p0);
            p1 = fmaf(xq.y, an[q4 * 4 + 1], p1);
            p2 = fmaf(xq.z, an[q4 * 4 + 2], p2);
            p3 = fmaf(xq.w, an[q4 * 4 + 3], p3);
        }
        float accP = (p0 + p1) + (p2 + p3);
        accP += __shfl_xor(accP, 16, 64);   // combine the 4 d-groups
        accP += __shfl_xor(accP, 32, 64);

        // ---- feature epilogues ----
        const float arg  = fminf(fmaxf(accR * sq2s - sR, -20.f), 20.f);
        const float prf  = expf(arg) * scaleR;
        const float pc   = fminf(fmaxf(accP, -1.f), 1.f);
        const float poly = pc * pc * 0.25f;

        // ---- stage per-wave, expand + write (no block barrier!) ----
        __builtin_amdgcn_wave_barrier();
        s_prf[wv][lane] = prf;
        if (lane < 16) s_poly[wv][lane] = poly;
        __builtin_amdgcn_wave_barrier();

        float* ob = out + (size_t)b * (NQUAD * NHEADS * PDIM * NFEAT)
                        + (size_t)h * (PDIM * NFEAT);
        #pragma unroll
        for (int i4 = 0; i4 < 4; ++i4) {
            const int rr = i4 >> 1;
            const int pp = (i4 * 8 + (lane >> 3)) & 15;
            const float pf = s_poly[wv][pp];
            const f32x4 pr = *(const f32x4*)&s_prf[wv][rr * 32 + (lane & 7) * 4];
            f32x4 v;
            v.x = pf * pr.x; v.y = pf * pr.y; v.z = pf * pr.z; v.w = pf * pr.w;
            *(f32x4*)(ob + (size_t)rr * (NHEADS * PDIM * NFEAT)
                         + (i4 & 1) * 256 + lane * 4) = v;
        }
    }
}

extern "C" void kernel_launch(void* const* d_in, const int* in_sizes, int n_in,
                              void* d_out, int out_size, void* d_ws, size_t ws_size,
                              hipStream_t stream)
{
    const float* x       = (const float*)d_in[0];
    const float* omega   = (const float*)d_in[1];
    const float* anchors = (const float*)d_in[2];
    const float* qn      = (const float*)d_in[3];
    const float* qw      = (const float*)d_in[4];
    float* out = (float*)d_out;

    const int Bsz = in_sizes[0] / (NHEADS * HDIM);          // 4096
    dim3 grid((Bsz / (WAVES_PB * GB)) * NHEADS);            // 128 * 16 = 2048
    slay_kernel<<<grid, 256, 0, stream>>>(x, omega, anchors, qn, qw, out);
}